// Round 16
// baseline (197.151 us; speedup 1.0000x reference)
//
#include <hip/hip_runtime.h>
#include <hip/hip_fp16.h>

#define MARGIN 6e-4f
#define RCAP 48

typedef __attribute__((ext_vector_type(8))) _Float16 half8;
typedef __attribute__((ext_vector_type(4))) float f32x4;

// RNE f32 -> fp16 bits (validated r12-r15)
__device__ __forceinline__ unsigned short f2h(float x) {
    __half h = __float2half(x);
    return *reinterpret_cast<unsigned short*>(&h);
}
__device__ __forceinline__ void gload16(const void* g, void* l) {
    __builtin_amdgcn_global_load_lds(
        (const __attribute__((address_space(1))) void*)g,
        (__attribute__((address_space(3))) void*)l, 16, 0, 0);
}

// ---------------------------------------------------------------------------
// k_prep v2: [0,512) fused z2 + z fp16 transpose (z read ONCE; r15's prep
// read z twice, once via a slow strided-scalar z2 section) | [512,516) e2 |
// [516,532) e fp16 swizzle | [532,548) rowCnt/lossAcc/doneCnt zero.
// NUMERICS: z2 = same single ascending-d fmaf chain per row (chunks staged
// sequentially d0 = 0,64,128,192; thread t owns row t) — bit-identical to
// the r1-validated chain. zh packing code is the r12-validated block.
// ---------------------------------------------------------------------------
__global__ __launch_bounds__(256) void k_prep(const float* __restrict__ z,
                                              const float* __restrict__ e,
                                              float* __restrict__ z2,
                                              float* __restrict__ e2,
                                              unsigned short* __restrict__ zh,
                                              unsigned short* __restrict__ eh,
                                              int* __restrict__ rowCnt,
                                              float* __restrict__ lossAcc,
                                              int* __restrict__ doneCnt) {
    __shared__ float tile[64][65];
    const int bi = blockIdx.x;
    const int t  = threadIdx.x;
    if (bi < 512) {                    // ---- fused z2 + zh ----
        const int n0 = bi * 64;
        const int b = n0 >> 10, nl0 = n0 & 1023;
        float s = 0.f;
        for (int c = 0; c < 4; ++c) {
            const int d0 = c * 64;
            __syncthreads();           // tile reuse guard (no-op at c=0)
#pragma unroll
            for (int i = 0; i < 4; ++i) {
                int flat = i * 256 + t;
                int dd = flat >> 4, q = flat & 15;
                float4 v = *(const float4*)(z + (size_t)b * 262144 +
                                            (size_t)(d0 + dd) * 1024 + nl0 + q * 4);
                tile[dd][q * 4 + 0] = v.x; tile[dd][q * 4 + 1] = v.y;
                tile[dd][q * 4 + 2] = v.z; tile[dd][q * 4 + 3] = v.w;
            }
            __syncthreads();
            if (t < 64) {              // ascending-d chain (bit-exact)
#pragma unroll 16
                for (int dd = 0; dd < 64; ++dd)
                    s = fmaf(tile[dd][t], tile[dd][t], s);
            }
            // pack zh with baked swizzle (r12-validated)
#pragma unroll
            for (int i = 0; i < 4; ++i) {
                int flat = i * 256 + t;
                int row = flat >> 4, ch = flat & 15;
                int s8p = ch >> 1, half = ch & 1;
                int s8  = s8p ^ (row & 7);
                int ddl = s8 * 8 + half * 4;
                unsigned int h[4];
#pragma unroll
                for (int m2 = 0; m2 < 4; ++m2)
                    h[m2] = f2h(tile[ddl + m2][row]);
                uint2 ph = { h[0] | (h[1] << 16), h[2] | (h[3] << 16) };
                size_t off = (size_t)(n0 + row) * 256 + d0 + s8p * 8 + half * 4;
                *(uint2*)(zh + off) = ph;
            }
        }
        if (t < 64) z2[n0 + t] = s;
    } else if (bi < 516) {             // ---- e2 (validated chain) ----
        int k = (bi - 512) * 256 + t;
        const float4* p = (const float4*)(e + (size_t)k * 256);
        float s = 0.f;
#pragma unroll 4
        for (int c = 0; c < 64; ++c) {
            float4 v = p[c];
            s = fmaf(v.x, v.x, s); s = fmaf(v.y, v.y, s);
            s = fmaf(v.z, v.z, s); s = fmaf(v.w, v.w, s);
        }
        e2[k] = s;
    } else if (bi < 532) {             // ---- e fp16 swizzle (validated) ----
        int k0 = (bi - 516) * 64;
#pragma unroll 4
        for (int i = 0; i < 16; ++i) {
            int flat = i * 256 + t;
            int row = flat >> 6, ch = flat & 63;
            int slab = ch >> 4, s8p = (ch >> 1) & 7, half = ch & 1;
            int s8 = s8p ^ (row & 7);
            int d  = slab * 64 + s8 * 8 + half * 4;
            float4 v = *(const float4*)(e + (size_t)(k0 + row) * 256 + d);
            uint2 ph = { (unsigned)f2h(v.x) | ((unsigned)f2h(v.y) << 16),
                         (unsigned)f2h(v.z) | ((unsigned)f2h(v.w) << 16) };
            size_t off = (size_t)(k0 + row) * 256 + slab * 64 + s8p * 8 + half * 4;
            *(uint2*)(eh + off) = ph;
        }
    } else {                           // ---- zeros ----
        int bb = bi - 532;             // 0..15
        if (bb == 0 && t == 0) { lossAcc[0] = 0.f; doneCnt[0] = 0; }
#pragma unroll
        for (int j = 0; j < 8; ++j)
            rowCnt[bb * 2048 + j * 256 + t] = 0;
    }
}

// ---------------------------------------------------------------------------
// k_score v3: persistent blocks, 512 x 512 thr, A-resident + 32-slab B
// stream (validated rounds 13-15, unchanged).
// ---------------------------------------------------------------------------
__global__ __launch_bounds__(512) void k_score(
        const unsigned short* __restrict__ zh,
        const unsigned short* __restrict__ eh,
        const float* __restrict__ e2,
        int* __restrict__ rowCnt, uint2* __restrict__ rowCand) {
    __shared__ unsigned short lds[32768];  // A[0,16384) | B0 | B1

    const int t    = threadIdx.x;          // 0..511
    const int lane = t & 63;
    const int w    = t >> 6;               // 0..7
    const int wr   = w >> 1;               // row-group 0..3
    const int wc   = w & 1;                // code-half 0..1
    const int c    = lane & 15;
    const int kq   = lane >> 4;            // 0..3
    const int n0   = blockIdx.x * 64;

#pragma unroll
    for (int p = 0; p < 4; ++p) {
        int slot = p * 512 + t;
        int row  = slot >> 5, sg = slot & 31;
        gload16(zh + (size_t)(n0 + row) * 256 + sg * 8,
                &lds[(p * 512 + w * 64) * 8]);
    }

#define STAGE_B(S, BUF)                                                      \
    do {                                                                     \
        int kc_ = (S) >> 2, dg_ = (S) & 3;                                   \
        _Pragma("unroll")                                                    \
        for (int p = 0; p < 2; ++p) {                                        \
            int slot = p * 512 + t;                                          \
            int code = slot >> 3, sg = slot & 7;                             \
            gload16(eh + (size_t)(kc_ * 128 + code) * 256 + dg_ * 64 + sg * 8, \
                    &lds[16384 + (BUF) * 8192 + (p * 512 + w * 64) * 8]);    \
        }                                                                    \
    } while (0)

    f32x4 acc[4];
#pragma unroll
    for (int cf = 0; cf < 4; ++cf) acc[cf] = (f32x4){0.f, 0.f, 0.f, 0.f};
    float m_run[4] = { 3.4e38f, 3.4e38f, 3.4e38f, 3.4e38f };

    const int rl = wr * 16 + c;
    STAGE_B(0, 0);
    __syncthreads();

    for (int s = 0; s < 32; ++s) {
        if (s < 31) STAGE_B(s + 1, (s + 1) & 1);
        {
            const int dg = s & 3;
            const unsigned short* Bb = &lds[16384 + (s & 1) * 8192];
#pragma unroll
            for (int ks = 0; ks < 2; ++ks) {
                int wo = ks * 4 + kq;
                half8 a = *(const half8*)&lds[rl * 256 + dg * 64 +
                                              (wo ^ (rl & 7)) * 8];
                half8 b[4];
#pragma unroll
                for (int cf = 0; cf < 4; ++cf) {
                    int cl = wc * 64 + cf * 16 + c;
                    b[cf] = *(const half8*)&Bb[cl * 64 + (wo ^ (cl & 7)) * 8];
                }
#pragma unroll
                for (int cf = 0; cf < 4; ++cf)
                    acc[cf] = __builtin_amdgcn_mfma_f32_16x16x32_f16(
                        a, b[cf], acc[cf], 0, 0, 0);
            }
        }
        if ((s & 3) == 3) {
            const int kc = s >> 2;
            float e2r[4];
#pragma unroll
            for (int cf = 0; cf < 4; ++cf)
                e2r[cf] = e2[kc * 128 + wc * 64 + cf * 16 + c];
            float mnew[4];
#pragma unroll
            for (int reg = 0; reg < 4; ++reg) {
                float mm = 3.4e38f;
#pragma unroll
                for (int cf = 0; cf < 4; ++cf)
                    mm = fminf(mm, fmaf(-2.f, acc[cf][reg], e2r[cf]));
                mnew[reg] = mm;
            }
#pragma unroll
            for (int m = 1; m < 16; m <<= 1)
#pragma unroll
                for (int reg = 0; reg < 4; ++reg)
                    mnew[reg] = fminf(mnew[reg], __shfl_xor(mnew[reg], m, 64));
#pragma unroll
            for (int reg = 0; reg < 4; ++reg)
                mnew[reg] = fminf(mnew[reg], m_run[reg]);
#pragma unroll
            for (int cf = 0; cf < 4; ++cf)
#pragma unroll
                for (int reg = 0; reg < 4; ++reg) {
                    float sv = fmaf(-2.f, acc[cf][reg], e2r[cf]);
                    if (sv <= mnew[reg] + MARGIN) {
                        int n = n0 + wr * 16 + kq * 4 + reg;
                        int k = kc * 128 + wc * 64 + cf * 16 + c;
                        int pos = atomicAdd(&rowCnt[n], 1);
                        if (pos < RCAP) {
                            uint2 cd; cd.x = (unsigned)k;
                            cd.y = __float_as_uint(sv);
                            rowCand[n * RCAP + pos] = cd;
                        }
                    }
                }
#pragma unroll
            for (int reg = 0; reg < 4; ++reg) m_run[reg] = mnew[reg];
#pragma unroll
            for (int cf = 0; cf < 4; ++cf) acc[cf] = (f32x4){0.f, 0.f, 0.f, 0.f};
        }
        __syncthreads();
    }
#undef STAGE_B
}

// ---------------------------------------------------------------------------
// k_sef: fused select + epilogue + finalize (replaces 3 dispatches).
// Block = 64 rows (grid 512 = (b, nl-chunk)).
// SELECT (thread-per-row, semantics provably identical to the validated
// lane-parallel r10-15 version: gmin = fmin over the same stored set; same
// survivor predicate; sole-survivor shortcut; exact rescore = validated
// ascending-d fp32 chain + fmaf(-2, ze, fl(z2+e2)); packed (distbits<<32|k)
// min == np first-index tie-break; cnt>RCAP -> deterministic full scan).
// EPILOGUE: 4 d-chunks; gather e[idx] slices into zqT[64][65] (writes 2/bank,
// reads 2/bank — free), stream z->out with float4 (4x256B segments/instr).
// FINALIZE: block loss sum -> 1 atomic/block -> last-block ticket writes
// vq_loss (removes k_final dispatch).
// ---------------------------------------------------------------------------
__global__ __launch_bounds__(256) void k_sef(
        const float* __restrict__ z, const float* __restrict__ e,
        const float* __restrict__ z2a, const float* __restrict__ e2,
        const int* __restrict__ rowCnt, const uint2* __restrict__ rowCand,
        float* __restrict__ outZ, float* __restrict__ outIdx,
        float* __restrict__ lossAcc, int* __restrict__ doneCnt,
        float* __restrict__ outLoss) {
    __shared__ float zqT[64][65];
    __shared__ int idxL[64];
    __shared__ float wsum[4];
    const int t   = threadIdx.x;
    const int b   = blockIdx.x >> 4;
    const int nl0 = (blockIdx.x & 15) * 64;
    const int n0  = b * 1024 + nl0;

    // ---- select phase: threads 0..63, one row each ----
    if (t < 64) {
        const int n = n0 + t;
        const int cnt = rowCnt[n];
        const float* zrow = z + (size_t)b * 262144 + nl0 + t;
        int bestK;
        if (cnt <= RCAP) {
            float gmin = 3.4e38f;
            for (int i = 0; i < cnt; ++i)
                gmin = fminf(gmin, __uint_as_float(rowCand[n * RCAP + i].y));
            int scnt = 0, soleK = 0;
            for (int i = 0; i < cnt; ++i) {
                uint2 cd = rowCand[n * RCAP + i];
                if (__uint_as_float(cd.y) <= gmin + MARGIN) { ++scnt; soleK = (int)cd.x; }
            }
            if (scnt == 1) {
                bestK = soleK;
            } else {
                const float z2r = z2a[n];
                unsigned long long key = 0xFFFFFFFFFFFFFFFFULL;
                for (int i = 0; i < cnt; ++i) {
                    uint2 cd = rowCand[n * RCAP + i];
                    if (__uint_as_float(cd.y) <= gmin + MARGIN) {
                        int k = (int)cd.x;
                        const float* er = e + (size_t)k * 256;
                        float ze = 0.f;
#pragma unroll 8
                        for (int d = 0; d < 256; ++d)
                            ze = fmaf(zrow[(size_t)d * 1024], er[d], ze);
                        float t1 = z2r + e2[k];
                        float dist = fmaf(-2.f, ze, t1);
                        unsigned long long kk =
                            ((unsigned long long)__float_as_uint(dist) << 32) |
                            (unsigned int)k;
                        if (kk < key) key = kk;
                    }
                }
                bestK = (int)(unsigned int)(key & 0xFFFFFFFFULL);
            }
        } else {                       // deterministic full-scan fallback
            const float z2r = z2a[n];
            unsigned long long key = 0xFFFFFFFFFFFFFFFFULL;
            for (int k = 0; k < 1024; ++k) {
                const float* er = e + (size_t)k * 256;
                float ze = 0.f;
#pragma unroll 8
                for (int d = 0; d < 256; ++d)
                    ze = fmaf(zrow[(size_t)d * 1024], er[d], ze);
                float t1 = z2r + e2[k];
                float dist = fmaf(-2.f, ze, t1);
                unsigned long long kk =
                    ((unsigned long long)__float_as_uint(dist) << 32) |
                    (unsigned int)k;
                if (kk < key) key = kk;
            }
            bestK = (int)(unsigned int)(key & 0xFFFFFFFFULL);
        }
        idxL[t] = bestK;
        outIdx[n] = (float)bestK;
    }
    __syncthreads();

    // ---- epilogue phase: 4 d-chunks of 64 ----
    float s = 0.f;
    for (int c = 0; c < 4; ++c) {
        const int d0 = c * 64;
        if (c) __syncthreads();        // zqT reuse guard
        if (t < 64) {                  // gather e slice (L2-resident)
            const float* er = e + (size_t)idxL[t] * 256 + d0;
#pragma unroll
            for (int q = 0; q < 16; ++q) {
                float4 v = *(const float4*)(er + q * 4);
                zqT[q * 4 + 0][t] = v.x; zqT[q * 4 + 1][t] = v.y;
                zqT[q * 4 + 2][t] = v.z; zqT[q * 4 + 3][t] = v.w;
            }
        }
        __syncthreads();
#pragma unroll
        for (int i = 0; i < 4; ++i) {
            int flat = i * 256 + t;
            int dd = flat >> 4, q = flat & 15;
            size_t go = (size_t)b * 262144 + (size_t)(d0 + dd) * 1024 + nl0 + q * 4;
            float4 z4 = *(const float4*)(z + go);
            float4 o; float df;
            df = zqT[dd][q * 4 + 0] - z4.x; s = fmaf(df, df, s); o.x = z4.x + df;
            df = zqT[dd][q * 4 + 1] - z4.y; s = fmaf(df, df, s); o.y = z4.y + df;
            df = zqT[dd][q * 4 + 2] - z4.z; s = fmaf(df, df, s); o.z = z4.z + df;
            df = zqT[dd][q * 4 + 3] - z4.w; s = fmaf(df, df, s); o.w = z4.w + df;
            *(float4*)(outZ + go) = o;
        }
    }

    // ---- loss reduce + last-block finalize ----
#pragma unroll
    for (int off = 32; off > 0; off >>= 1) s += __shfl_down(s, off, 64);
    if ((t & 63) == 0) wsum[t >> 6] = s;
    __syncthreads();
    if (t == 0) {
        float bs = ((wsum[0] + wsum[1]) + wsum[2]) + wsum[3];
        atomicAdd(lossAcc, bs);
        __threadfence();
        int tk = atomicAdd(doneCnt, 1);
        if (tk == 511) {               // all 512 blocks' adds visible
            float L = atomicAdd(lossAcc, 0.0f);
            float m = L * (1.0f / 8388608.0f);
            outLoss[0] = m + 0.25f * m;
        }
    }
}

// ---------------------------------------------------------------------------
extern "C" void kernel_launch(void* const* d_in, const int* in_sizes, int n_in,
                              void* d_out, int out_size, void* d_ws, size_t ws_size,
                              hipStream_t stream) {
    const float* z = (const float*)d_in[0];   // (32,256,32,32)
    const float* e = (const float*)d_in[1];   // (1024,256)
    float* out     = (float*)d_out;
    float* outIdx  = out + 8388608;
    float* outLoss = out + 8421376;

    float* z2      = (float*)d_ws;                        // 32768 f
    float* e2      = z2 + 32768;                          // 1024 f
    float* lossAcc = e2 + 1024;                           // 1 f
    int*   doneCnt = (int*)(lossAcc + 1);                 // 1 i
    int*   rowCnt  = doneCnt + 1;                         // 32768 i
    uintptr_t p = (uintptr_t)(rowCnt + 32768);
    p = (p + 255) & ~(uintptr_t)255;
    uint2* rowCand = (uint2*)p;                           // 32768*48 uint2 = 12 MB
    unsigned short* zh = (unsigned short*)(rowCand + 32768 * RCAP); // 16 MB
    unsigned short* eh = zh + 8388608;                    // 512 KB

    k_prep<<<548, 256, 0, stream>>>(z, e, z2, e2, zh, eh, rowCnt, lossAcc, doneCnt);
    k_score<<<512, 512, 0, stream>>>(zh, eh, e2, rowCnt, rowCand);
    k_sef<<<512, 256, 0, stream>>>(z, e, z2, e2, rowCnt, rowCand,
                                   out, outIdx, lossAcc, doneCnt, outLoss);
}